// Round 4
// baseline (2996.927 us; speedup 1.0000x reference)
//
#include <hip/hip_runtime.h>

// GCN 2-layer + mean pool — bucketed formulation.
//
// Nodes are grouped into buckets of 128 (bucket = dst >> 7, NB = ceil(n/128)).
// pass_a counting-sorts edges by bucket in LDS and writes packed keys
// ((src<<7)|local_dst) bucket-major with coalesced group writes.
// deg_dis computes degrees per bucket from the keys (LDS histogram).
// bucket_agg keeps agg[128][64] in LDS and accumulates gathered h-rows with
// ds_add_f32; self-loop/bias/relu fused; layer-2 variant folds straight into
// the channel-wise mean (no per-node materialization).
//
// ws: keys[NB*CAP] u32 | bcur[NB] int | dis[n] f32 | bufA[n*64] | bufB[n*64]

#define CAP 8192          // per-bucket capacity (avg ~4092 for E=3.2M, +64 sigma)
#define PA_T 28672        // edges per pass_a block (112 KB LDS keys)

__global__ __launch_bounds__(256)
void pass_a_kernel(const int* __restrict__ src, const int* __restrict__ dst,
                   int* __restrict__ bcur, unsigned* __restrict__ keys, int e, int nb) {
    __shared__ unsigned skeys[PA_T];   // 112 KB
    __shared__ int hist[1024];
    __shared__ int base[1024];
    __shared__ int gbase[1024];
    __shared__ int curs[1024];
    __shared__ int tscan[256];

    const int tid = threadIdx.x;
    const int e0 = blockIdx.x * PA_T;
    const int cnt = min(PA_T, e - e0);

    for (int i = tid; i < 1024; i += 256) hist[i] = 0;
    __syncthreads();

    // 1) histogram by bucket
    for (int i = tid; i < cnt; i += 256) {
        int d = dst[e0 + i];
        atomicAdd(&hist[d >> 7], 1);
    }
    __syncthreads();

    // 2) exclusive scan of hist[0..1023] (256 threads x 4)
    {
        int t4 = tid * 4;
        int a0 = hist[t4], a1 = hist[t4 + 1], a2 = hist[t4 + 2], a3 = hist[t4 + 3];
        int tsum = a0 + a1 + a2 + a3;
        tscan[tid] = tsum;
        __syncthreads();
        for (int off = 1; off < 256; off <<= 1) {
            int v = (tid >= off) ? tscan[tid - off] : 0;
            __syncthreads();
            tscan[tid] += v;
            __syncthreads();
        }
        int ex = tscan[tid] - tsum;
        base[t4] = ex;
        base[t4 + 1] = ex + a0;
        base[t4 + 2] = ex + a0 + a1;
        base[t4 + 3] = ex + a0 + a1 + a2;
    }
    __syncthreads();
    for (int i = tid; i < 1024; i += 256) curs[i] = base[i];
    __syncthreads();

    // 3) place keys into LDS, bucket-sorted
    for (int i = tid; i < cnt; i += 256) {
        int s = src[e0 + i], d = dst[e0 + i];
        int b = d >> 7;
        int pos = atomicAdd(&curs[b], 1);
        skeys[pos] = ((unsigned)s << 7) | (unsigned)(d & 127);
    }
    __syncthreads();

    // 4) reserve global group slots
    for (int b = tid; b < nb; b += 256) {
        int c = hist[b];
        gbase[b] = c ? atomicAdd(&bcur[b], c) : 0;
    }
    __syncthreads();

    // 5) coalesced group writes (wave per bucket, round-robin)
    const int wv = tid >> 6, lane = tid & 63;
    for (int b = wv; b < nb; b += 4) {
        int lb = base[b], c = hist[b], gb = gbase[b];
        unsigned* dp = keys + (size_t)b * CAP + gb;
        for (int i = lane; i < c; i += 64) dp[i] = skeys[lb + i];
    }
}

// Per-bucket degree histogram -> dis = rsqrt(deg+1)
__global__ __launch_bounds__(256)
void deg_dis_kernel(const unsigned* __restrict__ keys, const int* __restrict__ bcur,
                    float* __restrict__ dis, int n) {
    __shared__ int hist[128];
    const int tid = threadIdx.x;
    const int b = blockIdx.x;
    const int v0 = b << 7;
    if (tid < 128) hist[tid] = 0;
    __syncthreads();
    const int ne = bcur[b];
    const size_t kb = (size_t)b * CAP;
    for (int i = tid; i < ne; i += 256) atomicAdd(&hist[keys[kb + i] & 127u], 1);
    __syncthreads();
    if (tid < 128 && v0 + tid < n) dis[v0 + tid] = rsqrtf((float)hist[tid] + 1.0f);
}

// C[n x 64] = A[n x K] @ B[K x 64]
template <int K>
__global__ __launch_bounds__(256)
void gemm_kernel(const float* __restrict__ A, const float* __restrict__ B,
                 float* __restrict__ H, int n) {
    constexpr int KP = K + 4;
    __shared__ float As[64 * KP];
    __shared__ float Bs[K * 64];
    const int tid = threadIdx.x;
    const int row0 = blockIdx.x * 64;

    constexpr int A4 = 64 * (K / 4);
    for (int idx = tid; idx < A4; idx += 256) {
        int row = idx / (K / 4);
        int c4  = idx % (K / 4);
        float4 v = make_float4(0.f, 0.f, 0.f, 0.f);
        int r = row0 + row;
        if (r < n) v = *reinterpret_cast<const float4*>(A + (size_t)r * K + c4 * 4);
        *reinterpret_cast<float4*>(&As[row * KP + c4 * 4]) = v;
    }
    constexpr int B4 = K * 16;
    for (int idx = tid; idx < B4; idx += 256) {
        int row = idx / 16, c4 = idx % 16;
        *reinterpret_cast<float4*>(&Bs[row * 64 + c4 * 4]) =
            *reinterpret_cast<const float4*>(B + row * 64 + c4 * 4);
    }
    __syncthreads();

    const int tr = tid >> 4;
    const int tc = tid & 15;
    float acc[4][4];
#pragma unroll
    for (int j = 0; j < 4; ++j)
#pragma unroll
        for (int i = 0; i < 4; ++i) acc[j][i] = 0.f;

    for (int k4 = 0; k4 < K / 4; ++k4) {
        float4 a[4], bq[4];
#pragma unroll
        for (int j = 0; j < 4; ++j)
            a[j] = *reinterpret_cast<const float4*>(&As[(tr * 4 + j) * KP + k4 * 4]);
#pragma unroll
        for (int kk = 0; kk < 4; ++kk)
            bq[kk] = *reinterpret_cast<const float4*>(&Bs[(k4 * 4 + kk) * 64 + tc * 4]);
#pragma unroll
        for (int kk = 0; kk < 4; ++kk) {
#pragma unroll
            for (int j = 0; j < 4; ++j) {
                float av = (kk == 0) ? a[j].x : (kk == 1) ? a[j].y : (kk == 2) ? a[j].z : a[j].w;
                acc[j][0] = fmaf(av, bq[kk].x, acc[j][0]);
                acc[j][1] = fmaf(av, bq[kk].y, acc[j][1]);
                acc[j][2] = fmaf(av, bq[kk].z, acc[j][2]);
                acc[j][3] = fmaf(av, bq[kk].w, acc[j][3]);
            }
        }
    }

#pragma unroll
    for (int j = 0; j < 4; ++j) {
        int r = row0 + tr * 4 + j;
        if (r < n) {
            float4 v = make_float4(acc[j][0], acc[j][1], acc[j][2], acc[j][3]);
            *reinterpret_cast<float4*>(H + (size_t)r * 64 + tc * 4) = v;
        }
    }
}

// One block per bucket. agg[128][64] in LDS; wave-per-edge, lane = channel.
template <bool WRITE_OUT>
__global__ __launch_bounds__(256)
void bucket_agg_kernel(const unsigned* __restrict__ keys, const int* __restrict__ bcur,
                       const float* __restrict__ h, const float* __restrict__ dis,
                       const float* __restrict__ bias,
                       float* __restrict__ out, float* __restrict__ outsum,
                       int n, float inv_n) {
    __shared__ float agg[128 * 64];   // 32 KB
    __shared__ float ldis[128];
    __shared__ float lbias[64];
    __shared__ float red[256];

    const int tid = threadIdx.x;
    const int lane = tid & 63;
    const int wv = tid >> 6;
    const int b = blockIdx.x;
    const int v0 = b << 7;
    const int nv = min(128, n - v0);

    if (tid < 128) ldis[tid] = (tid < nv) ? dis[v0 + tid] : 0.f;
    if (tid < 64) lbias[tid] = bias[tid];
    __syncthreads();

    // self-loop init: agg[v][c] = h[v0+v][c] * dis^2
    const int tot = nv * 64;
    for (int idx = tid; idx < tot; idx += 256) {
        float dv = ldis[idx >> 6];
        agg[idx] = h[(size_t)v0 * 64 + idx] * dv * dv;
    }
    __syncthreads();

    const int ne = bcur[b];
    const size_t kb = (size_t)b * CAP;

    for (int eb = wv * 64; eb < ne; eb += 256) {
        const int m = min(64, ne - eb);
        unsigned kmine = (lane < m) ? keys[kb + eb + lane] : 0u;
        int j = 0;
        for (; j + 1 < m; j += 2) {
            unsigned k0 = __shfl(kmine, j);
            unsigned k1 = __shfl(kmine, j + 1);
            int s0 = k0 >> 7, l0 = k0 & 127;
            int s1 = k1 >> 7, l1 = k1 & 127;
            float w0 = dis[s0] * ldis[l0];
            float w1 = dis[s1] * ldis[l1];
            float h0 = h[(size_t)s0 * 64 + lane];
            float h1 = h[(size_t)s1 * 64 + lane];
            atomicAdd(&agg[l0 * 64 + lane], h0 * w0);
            atomicAdd(&agg[l1 * 64 + lane], h1 * w1);
        }
        if (j < m) {
            unsigned k0 = __shfl(kmine, j);
            int s0 = k0 >> 7, l0 = k0 & 127;
            atomicAdd(&agg[l0 * 64 + lane], h[(size_t)s0 * 64 + lane] * dis[s0] * ldis[l0]);
        }
    }
    __syncthreads();

    if (WRITE_OUT) {
        for (int idx = tid; idx < tot; idx += 256) {
            out[(size_t)v0 * 64 + idx] = fmaxf(agg[idx] + lbias[idx & 63], 0.f);
        }
    } else {
        float bsumv = 0.f;
        for (int idx = tid; idx < tot; idx += 256) {
            bsumv += fmaxf(agg[idx] + lbias[idx & 63], 0.f);   // idx&63 == tid&63
        }
        red[tid] = bsumv;
        __syncthreads();
        if (tid < 64) {
            float s = red[tid] + red[tid + 64] + red[tid + 128] + red[tid + 192];
            atomicAdd(&outsum[tid], s * inv_n);
        }
    }
}

extern "C" void kernel_launch(void* const* d_in, const int* in_sizes, int n_in,
                              void* d_out, int out_size, void* d_ws, size_t ws_size,
                              hipStream_t stream) {
    const float* x  = (const float*)d_in[0];
    const int*   ei = (const int*)d_in[1];
    const float* W1 = (const float*)d_in[2];
    const float* b1 = (const float*)d_in[3];
    const float* W2 = (const float*)d_in[4];
    const float* b2 = (const float*)d_in[5];

    const int n = in_sizes[0] / 128;   // 100000
    const int e = in_sizes[1] / 2;     // 3200000
    const int* src = ei;
    const int* dst = ei + e;
    const int nb = (n + 127) >> 7;     // 782 (must be <= 1024)

    char* ws = (char*)d_ws;
    size_t off = 0;
    auto alloc = [&](size_t bytes) { void* p = ws + off; off = (off + bytes + 255) & ~(size_t)255; return p; };
    unsigned* keys = (unsigned*)alloc((size_t)nb * CAP * 4);
    int*   bcur    = (int*)  alloc((size_t)nb * 4);
    float* dis     = (float*)alloc((size_t)n * 4);
    float* bufA    = (float*)alloc((size_t)n * 64 * 4);
    float* bufB    = (float*)alloc((size_t)n * 64 * 4);

    hipMemsetAsync(bcur, 0, (size_t)nb * 4, stream);
    hipMemsetAsync(d_out, 0, 64 * sizeof(float), stream);

    const int pa_blocks = (e + PA_T - 1) / PA_T;
    pass_a_kernel<<<pa_blocks, 256, 0, stream>>>(src, dst, bcur, keys, e, nb);
    deg_dis_kernel<<<nb, 256, 0, stream>>>(keys, bcur, dis, n);

    const int gblocks = (n + 63) / 64;
    // Layer 1: h1 = x@W1 -> bufA
    gemm_kernel<128><<<gblocks, 256, 0, stream>>>(x, W1, bufA, n);
    // x2 = relu(agg(h1) + b1) -> bufB
    bucket_agg_kernel<true><<<nb, 256, 0, stream>>>(keys, bcur, bufA, dis, b1,
                                                    bufB, nullptr, n, 0.f);
    // Layer 2: h2 = x2@W2 -> bufA
    gemm_kernel<64><<<gblocks, 256, 0, stream>>>(bufB, W2, bufA, n);
    // out = mean_n relu(agg(h2) + b2)
    bucket_agg_kernel<false><<<nb, 256, 0, stream>>>(keys, bcur, bufA, dis, b2,
                                                     nullptr, (float*)d_out, n, 1.0f / (float)n);
}

// Round 5
// 476.251 us; speedup vs baseline: 6.2927x; 6.2927x over previous
//
#include <hip/hip_runtime.h>

// GCN 2-layer + mean pool.
// Build: pass_a buckets edges by dst>>7 with coalesced key writes ->
//        bscan (bucket bases) -> bucket_csr (LDS counting-sort per bucket:
//        dis, rowptr, csr_src all written coalesced).
// Aggregate: wave-per-node CSR gather (4-deep unrolled), fused bias+relu;
//        layer 2 folds into channel-wise mean.
//
// ws: keys[NB*CAP] u32 | bcur[NB] int | bbase[NB] int | dis[n] f32 |
//     rowptr[n+1] int | csr_src[E] int | bufA[n*64] | bufB[n*64]

#define CAP 8192          // per-bucket capacity (avg ~4092, +64 sigma)
#define PA_T 28672        // edges per pass_a block (112 KB LDS keys)

__global__ __launch_bounds__(256)
void pass_a_kernel(const int* __restrict__ src, const int* __restrict__ dst,
                   int* __restrict__ bcur, unsigned* __restrict__ keys, int e, int nb) {
    __shared__ unsigned skeys[PA_T];   // 112 KB
    __shared__ int hist[1024];
    __shared__ int base[1024];
    __shared__ int gbase[1024];
    __shared__ int curs[1024];
    __shared__ int tscan[256];

    const int tid = threadIdx.x;
    const int e0 = blockIdx.x * PA_T;
    const int cnt = min(PA_T, e - e0);

    for (int i = tid; i < 1024; i += 256) hist[i] = 0;
    __syncthreads();

    for (int i = tid; i < cnt; i += 256) {
        int d = dst[e0 + i];
        atomicAdd(&hist[d >> 7], 1);
    }
    __syncthreads();

    {   // exclusive scan of hist[0..1023]
        int t4 = tid * 4;
        int a0 = hist[t4], a1 = hist[t4 + 1], a2 = hist[t4 + 2], a3 = hist[t4 + 3];
        int tsum = a0 + a1 + a2 + a3;
        tscan[tid] = tsum;
        __syncthreads();
        for (int off = 1; off < 256; off <<= 1) {
            int v = (tid >= off) ? tscan[tid - off] : 0;
            __syncthreads();
            tscan[tid] += v;
            __syncthreads();
        }
        int ex = tscan[tid] - tsum;
        base[t4] = ex;
        base[t4 + 1] = ex + a0;
        base[t4 + 2] = ex + a0 + a1;
        base[t4 + 3] = ex + a0 + a1 + a2;
    }
    __syncthreads();
    for (int i = tid; i < 1024; i += 256) curs[i] = base[i];
    __syncthreads();

    for (int i = tid; i < cnt; i += 256) {
        int s = src[e0 + i], d = dst[e0 + i];
        int b = d >> 7;
        int pos = atomicAdd(&curs[b], 1);
        skeys[pos] = ((unsigned)s << 7) | (unsigned)(d & 127);
    }
    __syncthreads();

    for (int b = tid; b < nb; b += 256) {
        int c = hist[b];
        gbase[b] = c ? atomicAdd(&bcur[b], c) : 0;
    }
    __syncthreads();

    const int wv = tid >> 6, lane = tid & 63;
    for (int b = wv; b < nb; b += 4) {
        int lb = base[b], c = hist[b], gb = gbase[b];
        unsigned* dp = keys + (size_t)b * CAP + gb;
        for (int i = lane; i < c; i += 64) dp[i] = skeys[lb + i];
    }
}

// Exclusive scan of bcur[nb] -> bbase[nb]; also rowptr[n] = total.
__global__ __launch_bounds__(1024)
void bscan_kernel(const int* __restrict__ bcur, int* __restrict__ bbase,
                  int* __restrict__ rowptr, int nb, int n) {
    __shared__ int lds[1024];
    int t = threadIdx.x;
    int v = (t < nb) ? bcur[t] : 0;
    lds[t] = v;
    __syncthreads();
    for (int off = 1; off < 1024; off <<= 1) {
        int a = (t >= off) ? lds[t - off] : 0;
        __syncthreads();
        lds[t] += a;
        __syncthreads();
    }
    if (t < nb) bbase[t] = lds[t] - v;
    if (t == 1023) rowptr[n] = lds[1023];
}

// One block per bucket: histogram -> dis + rowptr; LDS counting sort -> csr_src (coalesced).
__global__ __launch_bounds__(256)
void bucket_csr_kernel(const unsigned* __restrict__ keys, const int* __restrict__ bcur,
                       const int* __restrict__ bbase, float* __restrict__ dis,
                       int* __restrict__ rowptr, int* __restrict__ csr_src, int n) {
    __shared__ int ssrc[CAP];      // 32 KB
    __shared__ int hist[128];
    __shared__ int curs[128];
    __shared__ int sc[256];

    const int tid = threadIdx.x;
    const int b = blockIdx.x;
    const int v0 = b << 7;
    const int nv = min(128, n - v0);
    const int ne = bcur[b];
    const int gb = bbase[b];
    const size_t kb = (size_t)b * CAP;

    if (tid < 128) hist[tid] = 0;
    __syncthreads();
    for (int i = tid; i < ne; i += 256) atomicAdd(&hist[keys[kb + i] & 127u], 1);
    __syncthreads();

    // exclusive scan of hist[0..127]
    int hv = (tid < 128) ? hist[tid] : 0;
    sc[tid] = hv;
    __syncthreads();
    for (int off = 1; off < 128; off <<= 1) {
        int a = (tid >= off) ? sc[tid - off] : 0;
        __syncthreads();
        sc[tid] += a;
        __syncthreads();
    }
    if (tid < 128) {
        int ex = sc[tid] - hv;
        curs[tid] = ex;
        if (tid < nv) {
            rowptr[v0 + tid] = gb + ex;
            dis[v0 + tid] = rsqrtf((float)hv + 1.0f);
        }
    }
    __syncthreads();

    // counting-sort placement into LDS
    for (int i = tid; i < ne; i += 256) {
        unsigned k = keys[kb + i];
        int pos = atomicAdd(&curs[k & 127u], 1);
        ssrc[pos] = (int)(k >> 7);
    }
    __syncthreads();

    // coalesced write-out
    for (int i = tid; i < ne; i += 256) csr_src[gb + i] = ssrc[i];
}

// C[n x 64] = A[n x K] @ B[K x 64]
template <int K>
__global__ __launch_bounds__(256)
void gemm_kernel(const float* __restrict__ A, const float* __restrict__ B,
                 float* __restrict__ H, int n) {
    constexpr int KP = K + 4;
    __shared__ float As[64 * KP];
    __shared__ float Bs[K * 64];
    const int tid = threadIdx.x;
    const int row0 = blockIdx.x * 64;

    constexpr int A4 = 64 * (K / 4);
    for (int idx = tid; idx < A4; idx += 256) {
        int row = idx / (K / 4);
        int c4  = idx % (K / 4);
        float4 v = make_float4(0.f, 0.f, 0.f, 0.f);
        int r = row0 + row;
        if (r < n) v = *reinterpret_cast<const float4*>(A + (size_t)r * K + c4 * 4);
        *reinterpret_cast<float4*>(&As[row * KP + c4 * 4]) = v;
    }
    constexpr int B4 = K * 16;
    for (int idx = tid; idx < B4; idx += 256) {
        int row = idx / 16, c4 = idx % 16;
        *reinterpret_cast<float4*>(&Bs[row * 64 + c4 * 4]) =
            *reinterpret_cast<const float4*>(B + row * 64 + c4 * 4);
    }
    __syncthreads();

    const int tr = tid >> 4;
    const int tc = tid & 15;
    float acc[4][4];
#pragma unroll
    for (int j = 0; j < 4; ++j)
#pragma unroll
        for (int i = 0; i < 4; ++i) acc[j][i] = 0.f;

    for (int k4 = 0; k4 < K / 4; ++k4) {
        float4 a[4], bq[4];
#pragma unroll
        for (int j = 0; j < 4; ++j)
            a[j] = *reinterpret_cast<const float4*>(&As[(tr * 4 + j) * KP + k4 * 4]);
#pragma unroll
        for (int kk = 0; kk < 4; ++kk)
            bq[kk] = *reinterpret_cast<const float4*>(&Bs[(k4 * 4 + kk) * 64 + tc * 4]);
#pragma unroll
        for (int kk = 0; kk < 4; ++kk) {
#pragma unroll
            for (int j = 0; j < 4; ++j) {
                float av = (kk == 0) ? a[j].x : (kk == 1) ? a[j].y : (kk == 2) ? a[j].z : a[j].w;
                acc[j][0] = fmaf(av, bq[kk].x, acc[j][0]);
                acc[j][1] = fmaf(av, bq[kk].y, acc[j][1]);
                acc[j][2] = fmaf(av, bq[kk].z, acc[j][2]);
                acc[j][3] = fmaf(av, bq[kk].w, acc[j][3]);
            }
        }
    }

#pragma unroll
    for (int j = 0; j < 4; ++j) {
        int r = row0 + tr * 4 + j;
        if (r < n) {
            float4 v = make_float4(acc[j][0], acc[j][1], acc[j][2], acc[j][3]);
            *reinterpret_cast<float4*>(H + (size_t)r * 64 + tc * 4) = v;
        }
    }
}

// One wave per dst node (grid-stride). lane = channel. 4 gathers in flight.
template <bool WRITE_OUT>
__global__ __launch_bounds__(256)
void agg_kernel(const int* __restrict__ rowptr, const int* __restrict__ csr_src,
                const float* __restrict__ h, const float* __restrict__ dis,
                const float* __restrict__ bias,
                float* __restrict__ out, float* __restrict__ outsum,
                int n, float inv_n) {
    const int lane = threadIdx.x & 63;
    const int wid  = blockIdx.x * 4 + (threadIdx.x >> 6);
    const int nw   = gridDim.x * 4;
    const float b = bias[lane];
    float bsum = 0.f;

    for (int node = wid; node < n; node += nw) {
        const int st = rowptr[node];
        const int en = rowptr[node + 1];
        const float ds = dis[node];
        float acc = h[(size_t)node * 64 + lane] * ds * ds;
        int e = st;
        for (; e + 3 < en; e += 4) {
            int s0 = csr_src[e],     s1 = csr_src[e + 1];
            int s2 = csr_src[e + 2], s3 = csr_src[e + 3];
            float w0 = dis[s0] * ds, w1 = dis[s1] * ds;
            float w2 = dis[s2] * ds, w3 = dis[s3] * ds;
            float v0 = h[(size_t)s0 * 64 + lane];
            float v1 = h[(size_t)s1 * 64 + lane];
            float v2 = h[(size_t)s2 * 64 + lane];
            float v3 = h[(size_t)s3 * 64 + lane];
            acc = fmaf(v0, w0, acc);
            acc = fmaf(v1, w1, acc);
            acc = fmaf(v2, w2, acc);
            acc = fmaf(v3, w3, acc);
        }
        for (; e < en; ++e) {
            int s0 = csr_src[e];
            acc = fmaf(h[(size_t)s0 * 64 + lane], dis[s0] * ds, acc);
        }
        float val = fmaxf(acc + b, 0.f);
        if (WRITE_OUT) out[(size_t)node * 64 + lane] = val;
        else bsum += val;
    }

    if (!WRITE_OUT) {
        __shared__ float lds[256];
        lds[threadIdx.x] = bsum;
        __syncthreads();
        if (threadIdx.x < 64) {
            float s = lds[threadIdx.x] + lds[threadIdx.x + 64] +
                      lds[threadIdx.x + 128] + lds[threadIdx.x + 192];
            atomicAdd(&outsum[threadIdx.x], s * inv_n);
        }
    }
}

extern "C" void kernel_launch(void* const* d_in, const int* in_sizes, int n_in,
                              void* d_out, int out_size, void* d_ws, size_t ws_size,
                              hipStream_t stream) {
    const float* x  = (const float*)d_in[0];
    const int*   ei = (const int*)d_in[1];
    const float* W1 = (const float*)d_in[2];
    const float* b1 = (const float*)d_in[3];
    const float* W2 = (const float*)d_in[4];
    const float* b2 = (const float*)d_in[5];

    const int n = in_sizes[0] / 128;   // 100000
    const int e = in_sizes[1] / 2;     // 3200000
    const int* src = ei;
    const int* dst = ei + e;
    const int nb = (n + 127) >> 7;     // 782 (<= 1024)

    char* ws = (char*)d_ws;
    size_t off = 0;
    auto alloc = [&](size_t bytes) { void* p = ws + off; off = (off + bytes + 255) & ~(size_t)255; return p; };
    unsigned* keys = (unsigned*)alloc((size_t)nb * CAP * 4);
    int*   bcur    = (int*)  alloc((size_t)nb * 4);
    int*   bbase   = (int*)  alloc((size_t)nb * 4);
    float* dis     = (float*)alloc((size_t)n * 4);
    int*   rowptr  = (int*)  alloc((size_t)(n + 1) * 4);
    int*   csr_src = (int*)  alloc((size_t)e * 4);
    float* bufA    = (float*)alloc((size_t)n * 64 * 4);
    float* bufB    = (float*)alloc((size_t)n * 64 * 4);

    hipMemsetAsync(bcur, 0, (size_t)nb * 4, stream);
    hipMemsetAsync(d_out, 0, 64 * sizeof(float), stream);

    const int pa_blocks = (e + PA_T - 1) / PA_T;
    pass_a_kernel<<<pa_blocks, 256, 0, stream>>>(src, dst, bcur, keys, e, nb);
    bscan_kernel<<<1, 1024, 0, stream>>>(bcur, bbase, rowptr, nb, n);
    bucket_csr_kernel<<<nb, 256, 0, stream>>>(keys, bcur, bbase, dis, rowptr, csr_src, n);

    const int gblocks = (n + 63) / 64;
    // Layer 1: h1 = x@W1 -> bufA
    gemm_kernel<128><<<gblocks, 256, 0, stream>>>(x, W1, bufA, n);
    // x2 = relu(agg(h1) + b1) -> bufB
    agg_kernel<true><<<2048, 256, 0, stream>>>(rowptr, csr_src, bufA, dis, b1,
                                               bufB, nullptr, n, 0.f);
    // Layer 2: h2 = x2@W2 -> bufA
    gemm_kernel<64><<<gblocks, 256, 0, stream>>>(bufB, W2, bufA, n);
    // out = mean_n relu(agg(h2) + b2)
    agg_kernel<false><<<2048, 256, 0, stream>>>(rowptr, csr_src, bufA, dis, b2,
                                                nullptr, (float*)d_out, n, 1.0f / (float)n);
}

// Round 6
// 418.794 us; speedup vs baseline: 7.1561x; 1.1372x over previous
//
#include <hip/hip_runtime.h>

// GCN 2-layer + mean pool. bf16 feature tables (halved gather bytes), f32 math.
// Build: pass_a (bucket by dst>>7, coalesced) -> bscan -> bucket_csr (LDS sort).
// Aggregate: wave-per-node CSR gather, 8 gathers in flight, fused bias+relu;
// layer 2 folds into channel-wise mean.
//
// ws: keys[NB*CAP] u32 | bcur[NB] | bbase[NB] | dis[n] f32 | rowptr[n+1] |
//     csr_src[E] | bufA[n*64] bf16 | bufB[n*64] bf16

#define CAP 8192
#define PA_T 28672

__device__ __forceinline__ float bf2f(unsigned short u) {
    return __uint_as_float((unsigned)u << 16);
}
__device__ __forceinline__ unsigned short f2bf(float f) {
    unsigned u = __float_as_uint(f);
    u += 0x7FFFu + ((u >> 16) & 1u);   // round-nearest-even
    return (unsigned short)(u >> 16);
}

__global__ __launch_bounds__(256)
void pass_a_kernel(const int* __restrict__ src, const int* __restrict__ dst,
                   int* __restrict__ bcur, unsigned* __restrict__ keys, int e, int nb) {
    __shared__ unsigned skeys[PA_T];   // 112 KB
    __shared__ int hist[1024];
    __shared__ int base[1024];
    __shared__ int gbase[1024];
    __shared__ int curs[1024];
    __shared__ int tscan[256];

    const int tid = threadIdx.x;
    const int e0 = blockIdx.x * PA_T;
    const int cnt = min(PA_T, e - e0);

    for (int i = tid; i < 1024; i += 256) hist[i] = 0;
    __syncthreads();

    for (int i = tid; i < cnt; i += 256) {
        int d = dst[e0 + i];
        atomicAdd(&hist[d >> 7], 1);
    }
    __syncthreads();

    {   // exclusive scan of hist[0..1023]
        int t4 = tid * 4;
        int a0 = hist[t4], a1 = hist[t4 + 1], a2 = hist[t4 + 2], a3 = hist[t4 + 3];
        int tsum = a0 + a1 + a2 + a3;
        tscan[tid] = tsum;
        __syncthreads();
        for (int off = 1; off < 256; off <<= 1) {
            int v = (tid >= off) ? tscan[tid - off] : 0;
            __syncthreads();
            tscan[tid] += v;
            __syncthreads();
        }
        int ex = tscan[tid] - tsum;
        base[t4] = ex;
        base[t4 + 1] = ex + a0;
        base[t4 + 2] = ex + a0 + a1;
        base[t4 + 3] = ex + a0 + a1 + a2;
    }
    __syncthreads();
    for (int i = tid; i < 1024; i += 256) curs[i] = base[i];
    __syncthreads();

    for (int i = tid; i < cnt; i += 256) {
        int s = src[e0 + i], d = dst[e0 + i];
        int b = d >> 7;
        int pos = atomicAdd(&curs[b], 1);
        skeys[pos] = ((unsigned)s << 7) | (unsigned)(d & 127);
    }
    __syncthreads();

    for (int b = tid; b < nb; b += 256) {
        int c = hist[b];
        gbase[b] = c ? atomicAdd(&bcur[b], c) : 0;
    }
    __syncthreads();

    const int wv = tid >> 6, lane = tid & 63;
    for (int b = wv; b < nb; b += 4) {
        int lb = base[b], c = hist[b], gb = gbase[b];
        unsigned* dp = keys + (size_t)b * CAP + gb;
        for (int i = lane; i < c; i += 64) dp[i] = skeys[lb + i];
    }
}

__global__ __launch_bounds__(1024)
void bscan_kernel(const int* __restrict__ bcur, int* __restrict__ bbase,
                  int* __restrict__ rowptr, int nb, int n) {
    __shared__ int lds[1024];
    int t = threadIdx.x;
    int v = (t < nb) ? bcur[t] : 0;
    lds[t] = v;
    __syncthreads();
    for (int off = 1; off < 1024; off <<= 1) {
        int a = (t >= off) ? lds[t - off] : 0;
        __syncthreads();
        lds[t] += a;
        __syncthreads();
    }
    if (t < nb) bbase[t] = lds[t] - v;
    if (t == 1023) rowptr[n] = lds[1023];
}

__global__ __launch_bounds__(256)
void bucket_csr_kernel(const unsigned* __restrict__ keys, const int* __restrict__ bcur,
                       const int* __restrict__ bbase, float* __restrict__ dis,
                       int* __restrict__ rowptr, int* __restrict__ csr_src, int n) {
    __shared__ int ssrc[CAP];      // 32 KB
    __shared__ int hist[128];
    __shared__ int curs[128];
    __shared__ int sc[256];

    const int tid = threadIdx.x;
    const int b = blockIdx.x;
    const int v0 = b << 7;
    const int nv = min(128, n - v0);
    const int ne = bcur[b];
    const int gb = bbase[b];
    const size_t kb = (size_t)b * CAP;

    if (tid < 128) hist[tid] = 0;
    __syncthreads();
    for (int i = tid; i < ne; i += 256) atomicAdd(&hist[keys[kb + i] & 127u], 1);
    __syncthreads();

    int hv = (tid < 128) ? hist[tid] : 0;
    sc[tid] = hv;
    __syncthreads();
    for (int off = 1; off < 128; off <<= 1) {
        int a = (tid >= off) ? sc[tid - off] : 0;
        __syncthreads();
        sc[tid] += a;
        __syncthreads();
    }
    if (tid < 128) {
        int ex = sc[tid] - hv;
        curs[tid] = ex;
        if (tid < nv) {
            rowptr[v0 + tid] = gb + ex;
            dis[v0 + tid] = rsqrtf((float)hv + 1.0f);
        }
    }
    __syncthreads();

    for (int i = tid; i < ne; i += 256) {
        unsigned k = keys[kb + i];
        int pos = atomicAdd(&curs[k & 127u], 1);
        ssrc[pos] = (int)(k >> 7);
    }
    __syncthreads();

    for (int i = tid; i < ne; i += 256) csr_src[gb + i] = ssrc[i];
}

// C[n x 64] = A[n x K] @ B[K x 64]; A is f32 or bf16 per BF16_IN; C stored bf16.
template <int K, bool BF16_IN>
__global__ __launch_bounds__(256)
void gemm_kernel(const void* __restrict__ Av, const float* __restrict__ B,
                 unsigned short* __restrict__ H, int n) {
    constexpr int KP = K + 4;
    __shared__ float As[64 * KP];
    __shared__ float Bs[K * 64];
    const int tid = threadIdx.x;
    const int row0 = blockIdx.x * 64;

    constexpr int A4 = 64 * (K / 4);
    for (int idx = tid; idx < A4; idx += 256) {
        int row = idx / (K / 4);
        int c4  = idx % (K / 4);
        float4 v = make_float4(0.f, 0.f, 0.f, 0.f);
        int r = row0 + row;
        if (r < n) {
            if (BF16_IN) {
                const ushort4 t = *reinterpret_cast<const ushort4*>(
                    (const unsigned short*)Av + (size_t)r * K + c4 * 4);
                v = make_float4(bf2f(t.x), bf2f(t.y), bf2f(t.z), bf2f(t.w));
            } else {
                v = *reinterpret_cast<const float4*>((const float*)Av + (size_t)r * K + c4 * 4);
            }
        }
        *reinterpret_cast<float4*>(&As[row * KP + c4 * 4]) = v;
    }
    constexpr int B4 = K * 16;
    for (int idx = tid; idx < B4; idx += 256) {
        int row = idx / 16, c4 = idx % 16;
        *reinterpret_cast<float4*>(&Bs[row * 64 + c4 * 4]) =
            *reinterpret_cast<const float4*>(B + row * 64 + c4 * 4);
    }
    __syncthreads();

    const int tr = tid >> 4;
    const int tc = tid & 15;
    float acc[4][4];
#pragma unroll
    for (int j = 0; j < 4; ++j)
#pragma unroll
        for (int i = 0; i < 4; ++i) acc[j][i] = 0.f;

    for (int k4 = 0; k4 < K / 4; ++k4) {
        float4 a[4], bq[4];
#pragma unroll
        for (int j = 0; j < 4; ++j)
            a[j] = *reinterpret_cast<const float4*>(&As[(tr * 4 + j) * KP + k4 * 4]);
#pragma unroll
        for (int kk = 0; kk < 4; ++kk)
            bq[kk] = *reinterpret_cast<const float4*>(&Bs[(k4 * 4 + kk) * 64 + tc * 4]);
#pragma unroll
        for (int kk = 0; kk < 4; ++kk) {
#pragma unroll
            for (int j = 0; j < 4; ++j) {
                float av = (kk == 0) ? a[j].x : (kk == 1) ? a[j].y : (kk == 2) ? a[j].z : a[j].w;
                acc[j][0] = fmaf(av, bq[kk].x, acc[j][0]);
                acc[j][1] = fmaf(av, bq[kk].y, acc[j][1]);
                acc[j][2] = fmaf(av, bq[kk].z, acc[j][2]);
                acc[j][3] = fmaf(av, bq[kk].w, acc[j][3]);
            }
        }
    }

#pragma unroll
    for (int j = 0; j < 4; ++j) {
        int r = row0 + tr * 4 + j;
        if (r < n) {
            ushort4 o;
            o.x = f2bf(acc[j][0]); o.y = f2bf(acc[j][1]);
            o.z = f2bf(acc[j][2]); o.w = f2bf(acc[j][3]);
            *reinterpret_cast<ushort4*>(H + (size_t)r * 64 + tc * 4) = o;
        }
    }
}

// One wave per dst node (grid-stride). lane = channel. 8 bf16 gathers in flight.
template <bool WRITE_OUT>
__global__ __launch_bounds__(256)
void agg_kernel(const int* __restrict__ rowptr, const int* __restrict__ csr_src,
                const unsigned short* __restrict__ h, const float* __restrict__ dis,
                const float* __restrict__ bias,
                unsigned short* __restrict__ out, float* __restrict__ outsum,
                int n, float inv_n) {
    const int lane = threadIdx.x & 63;
    const int wid  = blockIdx.x * 4 + (threadIdx.x >> 6);
    const int nw   = gridDim.x * 4;
    const float b = bias[lane];
    float bsum = 0.f;

    for (int node = wid; node < n; node += nw) {
        const int st = rowptr[node];
        const int en = rowptr[node + 1];
        const float ds = dis[node];
        float acc = bf2f(h[(size_t)node * 64 + lane]) * ds * ds;
        int e = st;
        for (; e + 8 <= en; e += 8) {
            int s[8]; float w[8]; float hv[8];
#pragma unroll
            for (int k = 0; k < 8; ++k) s[k] = csr_src[e + k];
#pragma unroll
            for (int k = 0; k < 8; ++k) w[k] = dis[s[k]];
#pragma unroll
            for (int k = 0; k < 8; ++k) hv[k] = bf2f(h[(size_t)s[k] * 64 + lane]);
#pragma unroll
            for (int k = 0; k < 8; ++k) acc = fmaf(hv[k], w[k] * ds, acc);
        }
        for (; e < en; ++e) {
            int s0 = csr_src[e];
            acc = fmaf(bf2f(h[(size_t)s0 * 64 + lane]), dis[s0] * ds, acc);
        }
        float val = fmaxf(acc + b, 0.f);
        if (WRITE_OUT) out[(size_t)node * 64 + lane] = f2bf(val);
        else bsum += val;
    }

    if (!WRITE_OUT) {
        __shared__ float lds[256];
        lds[threadIdx.x] = bsum;
        __syncthreads();
        if (threadIdx.x < 64) {
            float s = lds[threadIdx.x] + lds[threadIdx.x + 64] +
                      lds[threadIdx.x + 128] + lds[threadIdx.x + 192];
            atomicAdd(&outsum[threadIdx.x], s * inv_n);
        }
    }
}

extern "C" void kernel_launch(void* const* d_in, const int* in_sizes, int n_in,
                              void* d_out, int out_size, void* d_ws, size_t ws_size,
                              hipStream_t stream) {
    const float* x  = (const float*)d_in[0];
    const int*   ei = (const int*)d_in[1];
    const float* W1 = (const float*)d_in[2];
    const float* b1 = (const float*)d_in[3];
    const float* W2 = (const float*)d_in[4];
    const float* b2 = (const float*)d_in[5];

    const int n = in_sizes[0] / 128;   // 100000
    const int e = in_sizes[1] / 2;     // 3200000
    const int* src = ei;
    const int* dst = ei + e;
    const int nb = (n + 127) >> 7;     // 782 (<= 1024)

    char* ws = (char*)d_ws;
    size_t off = 0;
    auto alloc = [&](size_t bytes) { void* p = ws + off; off = (off + bytes + 255) & ~(size_t)255; return p; };
    unsigned* keys = (unsigned*)alloc((size_t)nb * CAP * 4);
    int*   bcur    = (int*)  alloc((size_t)nb * 4);
    int*   bbase   = (int*)  alloc((size_t)nb * 4);
    float* dis     = (float*)alloc((size_t)n * 4);
    int*   rowptr  = (int*)  alloc((size_t)(n + 1) * 4);
    int*   csr_src = (int*)  alloc((size_t)e * 4);
    unsigned short* bufA = (unsigned short*)alloc((size_t)n * 64 * 2);
    unsigned short* bufB = (unsigned short*)alloc((size_t)n * 64 * 2);

    hipMemsetAsync(bcur, 0, (size_t)nb * 4, stream);
    hipMemsetAsync(d_out, 0, 64 * sizeof(float), stream);

    const int pa_blocks = (e + PA_T - 1) / PA_T;
    pass_a_kernel<<<pa_blocks, 256, 0, stream>>>(src, dst, bcur, keys, e, nb);
    bscan_kernel<<<1, 1024, 0, stream>>>(bcur, bbase, rowptr, nb, n);
    bucket_csr_kernel<<<nb, 256, 0, stream>>>(keys, bcur, bbase, dis, rowptr, csr_src, n);

    const int gblocks = (n + 63) / 64;
    // Layer 1: h1 = x@W1 -> bufA (bf16)
    gemm_kernel<128, false><<<gblocks, 256, 0, stream>>>(x, W1, bufA, n);
    // x2 = relu(agg(h1) + b1) -> bufB (bf16)
    agg_kernel<true><<<2048, 256, 0, stream>>>(rowptr, csr_src, bufA, dis, b1,
                                               bufB, nullptr, n, 0.f);
    // Layer 2: h2 = x2@W2 -> bufA (bf16)
    gemm_kernel<64, true><<<gblocks, 256, 0, stream>>>(bufB, W2, bufA, n);
    // out = mean_n relu(agg(h2) + b2)
    agg_kernel<false><<<2048, 256, 0, stream>>>(rowptr, csr_src, bufA, dis, b2,
                                                nullptr, (float*)d_out, n, 1.0f / (float)n);
}

// Round 7
// 399.867 us; speedup vs baseline: 7.4948x; 1.0473x over previous
//
#include <hip/hip_runtime.h>

// GCN 2-layer + mean pool. bf16 feature tables, f32 math.
// Build: pass_a (bucket by dst>>7, LDS counting sort, coalesced key writes)
//        -> bscan -> deg_dis (hist -> dis+rowptr) -> bucket_fill (LDS sort ->
//        packed csr_sn = {src, norm} written coalesced).
// Aggregate: wave-per-node CSR gather, software-pipelined 8-deep, predicated
//        tail; fused bias+relu; layer 2 folds into channel-wise mean.
//
// ws: keys[NB*CAP] u32 | bcur[NB] | bbase[NB] | dis[n] f32 | rowptr[n+1] |
//     csr_sn[E] int2 | bufA[n*64] bf16 | bufB[n*64] bf16

#define CAP 8192
#define PA_T 8192

__device__ __forceinline__ float bf2f(unsigned short u) {
    return __uint_as_float((unsigned)u << 16);
}
__device__ __forceinline__ unsigned short f2bf(float f) {
    unsigned u = __float_as_uint(f);
    u += 0x7FFFu + ((u >> 16) & 1u);   // round-nearest-even
    return (unsigned short)(u >> 16);
}

__global__ __launch_bounds__(256)
void pass_a_kernel(const int* __restrict__ src, const int* __restrict__ dst,
                   int* __restrict__ bcur, unsigned* __restrict__ keys, int e, int nb) {
    __shared__ unsigned skeys[PA_T];   // 32 KB
    __shared__ int hist[1024];
    __shared__ int base[1024];
    __shared__ int gbase[1024];
    __shared__ int curs[1024];
    __shared__ int tscan[256];

    const int tid = threadIdx.x;
    const int e0 = blockIdx.x * PA_T;
    const int cnt = min(PA_T, e - e0);

    for (int i = tid; i < 1024; i += 256) hist[i] = 0;
    __syncthreads();

    for (int i = tid; i < cnt; i += 256) {
        int d = dst[e0 + i];
        atomicAdd(&hist[d >> 7], 1);
    }
    __syncthreads();

    {   // exclusive scan of hist[0..1023]
        int t4 = tid * 4;
        int a0 = hist[t4], a1 = hist[t4 + 1], a2 = hist[t4 + 2], a3 = hist[t4 + 3];
        int tsum = a0 + a1 + a2 + a3;
        tscan[tid] = tsum;
        __syncthreads();
        for (int off = 1; off < 256; off <<= 1) {
            int v = (tid >= off) ? tscan[tid - off] : 0;
            __syncthreads();
            tscan[tid] += v;
            __syncthreads();
        }
        int ex = tscan[tid] - tsum;
        base[t4] = ex;
        base[t4 + 1] = ex + a0;
        base[t4 + 2] = ex + a0 + a1;
        base[t4 + 3] = ex + a0 + a1 + a2;
    }
    __syncthreads();
    for (int i = tid; i < 1024; i += 256) curs[i] = base[i];
    __syncthreads();

    for (int i = tid; i < cnt; i += 256) {
        int s = src[e0 + i], d = dst[e0 + i];
        int b = d >> 7;
        int pos = atomicAdd(&curs[b], 1);
        skeys[pos] = ((unsigned)s << 7) | (unsigned)(d & 127);
    }
    __syncthreads();

    for (int b = tid; b < nb; b += 256) {
        int c = hist[b];
        gbase[b] = c ? atomicAdd(&bcur[b], c) : 0;
    }
    __syncthreads();

    const int wv = tid >> 6, lane = tid & 63;
    for (int b = wv; b < nb; b += 4) {
        int lb = base[b], c = hist[b], gb = gbase[b];
        unsigned* dp = keys + (size_t)b * CAP + gb;
        for (int i = lane; i < c; i += 64) dp[i] = skeys[lb + i];
    }
}

__global__ __launch_bounds__(1024)
void bscan_kernel(const int* __restrict__ bcur, int* __restrict__ bbase,
                  int* __restrict__ rowptr, int nb, int n) {
    __shared__ int lds[1024];
    int t = threadIdx.x;
    int v = (t < nb) ? bcur[t] : 0;
    lds[t] = v;
    __syncthreads();
    for (int off = 1; off < 1024; off <<= 1) {
        int a = (t >= off) ? lds[t - off] : 0;
        __syncthreads();
        lds[t] += a;
        __syncthreads();
    }
    if (t < nb) bbase[t] = lds[t] - v;
    if (t == 1023) rowptr[n] = lds[1023];
}

// Per bucket: histogram -> dis + rowptr.
__global__ __launch_bounds__(256)
void deg_dis_kernel(const unsigned* __restrict__ keys, const int* __restrict__ bcur,
                    const int* __restrict__ bbase, float* __restrict__ dis,
                    int* __restrict__ rowptr, int n) {
    __shared__ int hist[128];
    __shared__ int sc[256];
    const int tid = threadIdx.x;
    const int b = blockIdx.x;
    const int v0 = b << 7;
    const int nv = min(128, n - v0);
    const int ne = bcur[b];
    const int gb = bbase[b];
    const size_t kb = (size_t)b * CAP;

    if (tid < 128) hist[tid] = 0;
    __syncthreads();
    for (int i = tid; i < ne; i += 256) atomicAdd(&hist[keys[kb + i] & 127u], 1);
    __syncthreads();

    int hv = (tid < 128) ? hist[tid] : 0;
    sc[tid] = hv;
    __syncthreads();
    for (int off = 1; off < 128; off <<= 1) {
        int a = (tid >= off) ? sc[tid - off] : 0;
        __syncthreads();
        sc[tid] += a;
        __syncthreads();
    }
    if (tid < nv) {
        rowptr[v0 + tid] = gb + sc[tid] - hv;
        dis[v0 + tid] = rsqrtf((float)hv + 1.0f);
    }
}

// Per bucket: LDS counting sort -> packed {src, norm} written coalesced.
__global__ __launch_bounds__(256)
void bucket_fill_kernel(const unsigned* __restrict__ keys, const int* __restrict__ bcur,
                        const int* __restrict__ bbase, const float* __restrict__ dis,
                        const int* __restrict__ rowptr, int2* __restrict__ csr_sn, int n) {
    __shared__ unsigned sk[CAP];   // 32 KB
    __shared__ int curs[128];
    __shared__ float ldis[128];

    const int tid = threadIdx.x;
    const int b = blockIdx.x;
    const int v0 = b << 7;
    const int nv = min(128, n - v0);
    const int ne = bcur[b];
    const int gb = bbase[b];
    const size_t kb = (size_t)b * CAP;

    if (tid < 128) {
        curs[tid] = (tid < nv) ? (rowptr[v0 + tid] - gb) : ne;
        ldis[tid] = (tid < nv) ? dis[v0 + tid] : 0.f;
    }
    __syncthreads();

    for (int i = tid; i < ne; i += 256) {
        unsigned k = keys[kb + i];
        int pos = atomicAdd(&curs[k & 127u], 1);
        sk[pos] = k;
    }
    __syncthreads();

    for (int i = tid; i < ne; i += 256) {
        unsigned k = sk[i];
        int s = (int)(k >> 7);
        float nrm = dis[s] * ldis[k & 127u];
        csr_sn[gb + i] = make_int2(s, __float_as_int(nrm));
    }
}

// C[n x 64] = A[n x K] @ B[K x 64]; A is f32 or bf16 per BF16_IN; C stored bf16.
template <int K, bool BF16_IN>
__global__ __launch_bounds__(256)
void gemm_kernel(const void* __restrict__ Av, const float* __restrict__ B,
                 unsigned short* __restrict__ H, int n) {
    constexpr int KP = K + 4;
    __shared__ float As[64 * KP];
    __shared__ float Bs[K * 64];
    const int tid = threadIdx.x;
    const int row0 = blockIdx.x * 64;

    constexpr int A4 = 64 * (K / 4);
    for (int idx = tid; idx < A4; idx += 256) {
        int row = idx / (K / 4);
        int c4  = idx % (K / 4);
        float4 v = make_float4(0.f, 0.f, 0.f, 0.f);
        int r = row0 + row;
        if (r < n) {
            if (BF16_IN) {
                const ushort4 t = *reinterpret_cast<const ushort4*>(
                    (const unsigned short*)Av + (size_t)r * K + c4 * 4);
                v = make_float4(bf2f(t.x), bf2f(t.y), bf2f(t.z), bf2f(t.w));
            } else {
                v = *reinterpret_cast<const float4*>((const float*)Av + (size_t)r * K + c4 * 4);
            }
        }
        *reinterpret_cast<float4*>(&As[row * KP + c4 * 4]) = v;
    }
    constexpr int B4 = K * 16;
    for (int idx = tid; idx < B4; idx += 256) {
        int row = idx / 16, c4 = idx % 16;
        *reinterpret_cast<float4*>(&Bs[row * 64 + c4 * 4]) =
            *reinterpret_cast<const float4*>(B + row * 64 + c4 * 4);
    }
    __syncthreads();

    const int tr = tid >> 4;
    const int tc = tid & 15;
    float acc[4][4];
#pragma unroll
    for (int j = 0; j < 4; ++j)
#pragma unroll
        for (int i = 0; i < 4; ++i) acc[j][i] = 0.f;

    for (int k4 = 0; k4 < K / 4; ++k4) {
        float4 a[4], bq[4];
#pragma unroll
        for (int j = 0; j < 4; ++j)
            a[j] = *reinterpret_cast<const float4*>(&As[(tr * 4 + j) * KP + k4 * 4]);
#pragma unroll
        for (int kk = 0; kk < 4; ++kk)
            bq[kk] = *reinterpret_cast<const float4*>(&Bs[(k4 * 4 + kk) * 64 + tc * 4]);
#pragma unroll
        for (int kk = 0; kk < 4; ++kk) {
#pragma unroll
            for (int j = 0; j < 4; ++j) {
                float av = (kk == 0) ? a[j].x : (kk == 1) ? a[j].y : (kk == 2) ? a[j].z : a[j].w;
                acc[j][0] = fmaf(av, bq[kk].x, acc[j][0]);
                acc[j][1] = fmaf(av, bq[kk].y, acc[j][1]);
                acc[j][2] = fmaf(av, bq[kk].z, acc[j][2]);
                acc[j][3] = fmaf(av, bq[kk].w, acc[j][3]);
            }
        }
    }

#pragma unroll
    for (int j = 0; j < 4; ++j) {
        int r = row0 + tr * 4 + j;
        if (r < n) {
            ushort4 o;
            o.x = f2bf(acc[j][0]); o.y = f2bf(acc[j][1]);
            o.z = f2bf(acc[j][2]); o.w = f2bf(acc[j][3]);
            *reinterpret_cast<ushort4*>(H + (size_t)r * 64 + tc * 4) = o;
        }
    }
}

// One wave per dst node. lane = channel. Software-pipelined 8-deep gathers,
// predicated tail chunk (no serial remainder).
template <bool WRITE_OUT>
__global__ __launch_bounds__(256)
void agg_kernel(const int* __restrict__ rowptr, const int2* __restrict__ csr_sn,
                const unsigned short* __restrict__ h, const float* __restrict__ dis,
                const float* __restrict__ bias,
                unsigned short* __restrict__ out, float* __restrict__ outsum,
                int n, float inv_n) {
    const int lane = threadIdx.x & 63;
    const int wid  = blockIdx.x * 4 + (threadIdx.x >> 6);
    const int nw   = gridDim.x * 4;
    const float b = bias[lane];
    float bsum = 0.f;

    for (int node = wid; node < n; node += nw) {
        const int st = rowptr[node];
        const int en = rowptr[node + 1];
        const float ds = dis[node];
        float acc = bf2f(h[(size_t)node * 64 + lane]) * ds * ds;
        int e = st;

        int sA[8]; float nA[8];
        if (e + 8 <= en) {
#pragma unroll
            for (int k = 0; k < 8; ++k) {
                int2 sn = csr_sn[e + k];
                sA[k] = sn.x; nA[k] = __int_as_float(sn.y);
            }
        }
        for (; e + 16 <= en; e += 8) {
            float hv[8];
#pragma unroll
            for (int k = 0; k < 8; ++k) hv[k] = bf2f(h[(size_t)sA[k] * 64 + lane]);
            int sB[8]; float nB[8];
#pragma unroll
            for (int k = 0; k < 8; ++k) {
                int2 sn = csr_sn[e + 8 + k];
                sB[k] = sn.x; nB[k] = __int_as_float(sn.y);
            }
#pragma unroll
            for (int k = 0; k < 8; ++k) acc = fmaf(hv[k], nA[k], acc);
#pragma unroll
            for (int k = 0; k < 8; ++k) { sA[k] = sB[k]; nA[k] = nB[k]; }
        }
        if (e + 8 <= en) {
            float hv[8];
#pragma unroll
            for (int k = 0; k < 8; ++k) hv[k] = bf2f(h[(size_t)sA[k] * 64 + lane]);
#pragma unroll
            for (int k = 0; k < 8; ++k) acc = fmaf(hv[k], nA[k], acc);
            e += 8;
        }
        if (e < en) {   // 1..7 edges, all issued in parallel
            float hv[8], nt[8];
#pragma unroll
            for (int k = 0; k < 8; ++k) {
                int idx = (e + k < en) ? (e + k) : st;
                int2 sn = csr_sn[idx];
                nt[k] = (e + k < en) ? __int_as_float(sn.y) : 0.f;
                hv[k] = bf2f(h[(size_t)sn.x * 64 + lane]);
            }
#pragma unroll
            for (int k = 0; k < 8; ++k) acc = fmaf(hv[k], nt[k], acc);
        }

        float val = fmaxf(acc + b, 0.f);
        if (WRITE_OUT) out[(size_t)node * 64 + lane] = f2bf(val);
        else bsum += val;
    }

    if (!WRITE_OUT) {
        __shared__ float lds[256];
        lds[threadIdx.x] = bsum;
        __syncthreads();
        if (threadIdx.x < 64) {
            float s = lds[threadIdx.x] + lds[threadIdx.x + 64] +
                      lds[threadIdx.x + 128] + lds[threadIdx.x + 192];
            atomicAdd(&outsum[threadIdx.x], s * inv_n);
        }
    }
}

extern "C" void kernel_launch(void* const* d_in, const int* in_sizes, int n_in,
                              void* d_out, int out_size, void* d_ws, size_t ws_size,
                              hipStream_t stream) {
    const float* x  = (const float*)d_in[0];
    const int*   ei = (const int*)d_in[1];
    const float* W1 = (const float*)d_in[2];
    const float* b1 = (const float*)d_in[3];
    const float* W2 = (const float*)d_in[4];
    const float* b2 = (const float*)d_in[5];

    const int n = in_sizes[0] / 128;   // 100000
    const int e = in_sizes[1] / 2;     // 3200000
    const int* src = ei;
    const int* dst = ei + e;
    const int nb = (n + 127) >> 7;     // 782 (<= 1024)

    char* ws = (char*)d_ws;
    size_t off = 0;
    auto alloc = [&](size_t bytes) { void* p = ws + off; off = (off + bytes + 255) & ~(size_t)255; return p; };
    unsigned* keys = (unsigned*)alloc((size_t)nb * CAP * 4);
    int*   bcur    = (int*)  alloc((size_t)nb * 4);
    int*   bbase   = (int*)  alloc((size_t)nb * 4);
    float* dis     = (float*)alloc((size_t)n * 4);
    int*   rowptr  = (int*)  alloc((size_t)(n + 1) * 4);
    int2*  csr_sn  = (int2*) alloc((size_t)e * 8);
    unsigned short* bufA = (unsigned short*)alloc((size_t)n * 64 * 2);
    unsigned short* bufB = (unsigned short*)alloc((size_t)n * 64 * 2);

    hipMemsetAsync(bcur, 0, (size_t)nb * 4, stream);
    hipMemsetAsync(d_out, 0, 64 * sizeof(float), stream);

    const int pa_blocks = (e + PA_T - 1) / PA_T;
    pass_a_kernel<<<pa_blocks, 256, 0, stream>>>(src, dst, bcur, keys, e, nb);
    bscan_kernel<<<1, 1024, 0, stream>>>(bcur, bbase, rowptr, nb, n);
    deg_dis_kernel<<<nb, 256, 0, stream>>>(keys, bcur, bbase, dis, rowptr, n);
    bucket_fill_kernel<<<nb, 256, 0, stream>>>(keys, bcur, bbase, dis, rowptr, csr_sn, n);

    const int gblocks = (n + 63) / 64;
    // Layer 1: h1 = x@W1 -> bufA (bf16)
    gemm_kernel<128, false><<<gblocks, 256, 0, stream>>>(x, W1, bufA, n);
    // x2 = relu(agg(h1) + b1) -> bufB (bf16)
    agg_kernel<true><<<2048, 256, 0, stream>>>(rowptr, csr_sn, bufA, dis, b1,
                                               bufB, nullptr, n, 0.f);
    // Layer 2: h2 = x2@W2 -> bufA (bf16)
    gemm_kernel<64, true><<<gblocks, 256, 0, stream>>>(bufB, W2, bufA, n);
    // out = mean_n relu(agg(h2) + b2)
    agg_kernel<false><<<2048, 256, 0, stream>>>(rowptr, csr_sn, bufA, dis, b2,
                                                nullptr, (float*)d_out, n, 1.0f / (float)n);
}

// Round 8
// 349.805 us; speedup vs baseline: 8.5674x; 1.1431x over previous
//
#include <hip/hip_runtime.h>

// GCN 2-layer + mean pool. bf16 feature tables, f32 math.
// Build: pass_a (bucket by dst>>7) -> bscan -> deg_dis -> bucket_fill
//        (csr_sn = {src<<7 byte-offset, norm} coalesced).
// Aggregate: wave-per-node, QUAD-SPLIT gather: lane=(q,cl), each uint2 load
//        instruction fetches 4 source rows (one per quarter-wave). Fused
//        bias+relu; layer 2 folds into channel-wise mean.

#define CAP 8192
#define PA_T 8192

__device__ __forceinline__ float bflo(unsigned u) { return __uint_as_float(u << 16); }
__device__ __forceinline__ float bfhi(unsigned u) { return __uint_as_float(u & 0xFFFF0000u); }
__device__ __forceinline__ unsigned short f2bf(float f) {
    unsigned u = __float_as_uint(f);
    u += 0x7FFFu + ((u >> 16) & 1u);
    return (unsigned short)(u >> 16);
}

__global__ __launch_bounds__(256)
void pass_a_kernel(const int* __restrict__ src, const int* __restrict__ dst,
                   int* __restrict__ bcur, unsigned* __restrict__ keys, int e, int nb) {
    __shared__ unsigned skeys[PA_T];   // 32 KB
    __shared__ int hist[1024];
    __shared__ int base[1024];
    __shared__ int gbase[1024];
    __shared__ int curs[1024];
    __shared__ int tscan[256];

    const int tid = threadIdx.x;
    const int e0 = blockIdx.x * PA_T;
    const int cnt = min(PA_T, e - e0);

    for (int i = tid; i < 1024; i += 256) hist[i] = 0;
    __syncthreads();

    for (int i = tid; i < cnt; i += 256) {
        int d = dst[e0 + i];
        atomicAdd(&hist[d >> 7], 1);
    }
    __syncthreads();

    {   // exclusive scan of hist[0..1023]
        int t4 = tid * 4;
        int a0 = hist[t4], a1 = hist[t4 + 1], a2 = hist[t4 + 2], a3 = hist[t4 + 3];
        int tsum = a0 + a1 + a2 + a3;
        tscan[tid] = tsum;
        __syncthreads();
        for (int off = 1; off < 256; off <<= 1) {
            int v = (tid >= off) ? tscan[tid - off] : 0;
            __syncthreads();
            tscan[tid] += v;
            __syncthreads();
        }
        int ex = tscan[tid] - tsum;
        base[t4] = ex;
        base[t4 + 1] = ex + a0;
        base[t4 + 2] = ex + a0 + a1;
        base[t4 + 3] = ex + a0 + a1 + a2;
    }
    __syncthreads();
    for (int i = tid; i < 1024; i += 256) curs[i] = base[i];
    __syncthreads();

    for (int i = tid; i < cnt; i += 256) {
        int s = src[e0 + i], d = dst[e0 + i];
        int b = d >> 7;
        int pos = atomicAdd(&curs[b], 1);
        skeys[pos] = ((unsigned)s << 7) | (unsigned)(d & 127);
    }
    __syncthreads();

    for (int b = tid; b < nb; b += 256) {
        int c = hist[b];
        gbase[b] = c ? atomicAdd(&bcur[b], c) : 0;
    }
    __syncthreads();

    const int wv = tid >> 6, lane = tid & 63;
    for (int b = wv; b < nb; b += 4) {
        int lb = base[b], c = hist[b], gb = gbase[b];
        unsigned* dp = keys + (size_t)b * CAP + gb;
        for (int i = lane; i < c; i += 64) dp[i] = skeys[lb + i];
    }
}

__global__ __launch_bounds__(1024)
void bscan_kernel(const int* __restrict__ bcur, int* __restrict__ bbase,
                  int* __restrict__ rowptr, int nb, int n) {
    __shared__ int lds[1024];
    int t = threadIdx.x;
    int v = (t < nb) ? bcur[t] : 0;
    lds[t] = v;
    __syncthreads();
    for (int off = 1; off < 1024; off <<= 1) {
        int a = (t >= off) ? lds[t - off] : 0;
        __syncthreads();
        lds[t] += a;
        __syncthreads();
    }
    if (t < nb) bbase[t] = lds[t] - v;
    if (t == 1023) rowptr[n] = lds[1023];
}

__global__ __launch_bounds__(256)
void deg_dis_kernel(const unsigned* __restrict__ keys, const int* __restrict__ bcur,
                    const int* __restrict__ bbase, float* __restrict__ dis,
                    int* __restrict__ rowptr, int n) {
    __shared__ int hist[128];
    __shared__ int sc[256];
    const int tid = threadIdx.x;
    const int b = blockIdx.x;
    const int v0 = b << 7;
    const int nv = min(128, n - v0);
    const int ne = bcur[b];
    const int gb = bbase[b];
    const size_t kb = (size_t)b * CAP;

    if (tid < 128) hist[tid] = 0;
    __syncthreads();
    for (int i = tid; i < ne; i += 256) atomicAdd(&hist[keys[kb + i] & 127u], 1);
    __syncthreads();

    int hv = (tid < 128) ? hist[tid] : 0;
    sc[tid] = hv;
    __syncthreads();
    for (int off = 1; off < 128; off <<= 1) {
        int a = (tid >= off) ? sc[tid - off] : 0;
        __syncthreads();
        sc[tid] += a;
        __syncthreads();
    }
    if (tid < nv) {
        rowptr[v0 + tid] = gb + sc[tid] - hv;
        dis[v0 + tid] = rsqrtf((float)hv + 1.0f);
    }
}

// Per bucket: LDS counting sort -> packed {src byte-offset, norm} coalesced.
__global__ __launch_bounds__(256)
void bucket_fill_kernel(const unsigned* __restrict__ keys, const int* __restrict__ bcur,
                        const int* __restrict__ bbase, const float* __restrict__ dis,
                        const int* __restrict__ rowptr, int2* __restrict__ csr_sn, int n) {
    __shared__ unsigned sk[CAP];   // 32 KB
    __shared__ int curs[128];
    __shared__ float ldis[128];

    const int tid = threadIdx.x;
    const int b = blockIdx.x;
    const int v0 = b << 7;
    const int nv = min(128, n - v0);
    const int ne = bcur[b];
    const int gb = bbase[b];
    const size_t kb = (size_t)b * CAP;

    if (tid < 128) {
        curs[tid] = (tid < nv) ? (rowptr[v0 + tid] - gb) : ne;
        ldis[tid] = (tid < nv) ? dis[v0 + tid] : 0.f;
    }
    __syncthreads();

    for (int i = tid; i < ne; i += 256) {
        unsigned k = keys[kb + i];
        int pos = atomicAdd(&curs[k & 127u], 1);
        sk[pos] = k;
    }
    __syncthreads();

    for (int i = tid; i < ne; i += 256) {
        unsigned k = sk[i];
        int s = (int)(k >> 7);
        float nrm = dis[s] * ldis[k & 127u];
        // x = s*128 = byte offset into bf16 row table
        csr_sn[gb + i] = make_int2((int)(k & 0xFFFFFF80u), __float_as_int(nrm));
    }
}

// C[n x 64] = A[n x K] @ B[K x 64]; A is f32 or bf16 per BF16_IN; C stored bf16.
template <int K, bool BF16_IN>
__global__ __launch_bounds__(256)
void gemm_kernel(const void* __restrict__ Av, const float* __restrict__ B,
                 unsigned short* __restrict__ H, int n) {
    constexpr int KP = K + 4;
    __shared__ float As[64 * KP];
    __shared__ float Bs[K * 64];
    const int tid = threadIdx.x;
    const int row0 = blockIdx.x * 64;

    constexpr int A4 = 64 * (K / 4);
    for (int idx = tid; idx < A4; idx += 256) {
        int row = idx / (K / 4);
        int c4  = idx % (K / 4);
        float4 v = make_float4(0.f, 0.f, 0.f, 0.f);
        int r = row0 + row;
        if (r < n) {
            if (BF16_IN) {
                const uint2 t = *reinterpret_cast<const uint2*>(
                    (const unsigned short*)Av + (size_t)r * K + c4 * 4);
                v = make_float4(bflo(t.x), bfhi(t.x), bflo(t.y), bfhi(t.y));
            } else {
                v = *reinterpret_cast<const float4*>((const float*)Av + (size_t)r * K + c4 * 4);
            }
        }
        *reinterpret_cast<float4*>(&As[row * KP + c4 * 4]) = v;
    }
    constexpr int B4 = K * 16;
    for (int idx = tid; idx < B4; idx += 256) {
        int row = idx / 16, c4 = idx % 16;
        *reinterpret_cast<float4*>(&Bs[row * 64 + c4 * 4]) =
            *reinterpret_cast<const float4*>(B + row * 64 + c4 * 4);
    }
    __syncthreads();

    const int tr = tid >> 4;
    const int tc = tid & 15;
    float acc[4][4];
#pragma unroll
    for (int j = 0; j < 4; ++j)
#pragma unroll
        for (int i = 0; i < 4; ++i) acc[j][i] = 0.f;

    for (int k4 = 0; k4 < K / 4; ++k4) {
        float4 a[4], bq[4];
#pragma unroll
        for (int j = 0; j < 4; ++j)
            a[j] = *reinterpret_cast<const float4*>(&As[(tr * 4 + j) * KP + k4 * 4]);
#pragma unroll
        for (int kk = 0; kk < 4; ++kk)
            bq[kk] = *reinterpret_cast<const float4*>(&Bs[(k4 * 4 + kk) * 64 + tc * 4]);
#pragma unroll
        for (int kk = 0; kk < 4; ++kk) {
#pragma unroll
            for (int j = 0; j < 4; ++j) {
                float av = (kk == 0) ? a[j].x : (kk == 1) ? a[j].y : (kk == 2) ? a[j].z : a[j].w;
                acc[j][0] = fmaf(av, bq[kk].x, acc[j][0]);
                acc[j][1] = fmaf(av, bq[kk].y, acc[j][1]);
                acc[j][2] = fmaf(av, bq[kk].z, acc[j][2]);
                acc[j][3] = fmaf(av, bq[kk].w, acc[j][3]);
            }
        }
    }

#pragma unroll
    for (int j = 0; j < 4; ++j) {
        int r = row0 + tr * 4 + j;
        if (r < n) {
            ushort4 o;
            o.x = f2bf(acc[j][0]); o.y = f2bf(acc[j][1]);
            o.z = f2bf(acc[j][2]); o.w = f2bf(acc[j][3]);
            *reinterpret_cast<ushort4*>(H + (size_t)r * 64 + tc * 4) = o;
        }
    }
}

// One wave per dst node. lane = (q = lane>>4, cl = lane&15).
// Each uint2 gather instruction fetches 4 source rows (one per quarter-wave):
// lane handles channels cl*4..cl*4+3 of edge e+q. Cross-quarter shfl_xor
// reduce per node. Tail edges masked with norm=0.
template <bool WRITE_OUT>
__global__ __launch_bounds__(256)
void agg_kernel(const int* __restrict__ rowptr, const int2* __restrict__ csr_sn,
                const unsigned short* __restrict__ h, const float* __restrict__ dis,
                const float* __restrict__ bias,
                unsigned short* __restrict__ out, float* __restrict__ outsum,
                int n, float inv_n) {
    const int tid = threadIdx.x;
    const int lane = tid & 63;
    const int q = lane >> 4;
    const int cl = lane & 15;
    const int wid = blockIdx.x * 4 + (tid >> 6);
    const int nw = gridDim.x * 4;
    const char* hb = (const char*)h;
    const float4 bias4 = *reinterpret_cast<const float4*>(bias + cl * 4);
    float4 bsum = make_float4(0.f, 0.f, 0.f, 0.f);

    for (int node = wid; node < n; node += nw) {
        const int st = rowptr[node];
        const int en = rowptr[node + 1];
        const float ds = dis[node];

        // self-loop (quarter 0 only; others multiply by 0)
        float4 acc;
        {
            uint2 hw = *reinterpret_cast<const uint2*>(hb + (size_t)node * 128 + cl * 8);
            float s2 = (q == 0) ? ds * ds : 0.f;
            acc.x = bflo(hw.x) * s2;
            acc.y = bfhi(hw.x) * s2;
            acc.z = bflo(hw.y) * s2;
            acc.w = bfhi(hw.y) * s2;
        }

        if (en > st) {
            // masked sn load for this lane's edge in a quad starting at base
            auto ldsn = [&](int bse) -> int2 {
                int idx = bse + q;
                int2 sn = csr_sn[min(idx, en - 1)];
                if (idx >= en) sn.y = 0;
                return sn;
            };
            int e = st;
            int2 sA = ldsn(e);
            int2 sB = ldsn(e + 4);
            for (; e < en; e += 8) {
                uint2 hA = *reinterpret_cast<const uint2*>(hb + (size_t)(unsigned)sA.x + cl * 8);
                uint2 hB = *reinterpret_cast<const uint2*>(hb + (size_t)(unsigned)sB.x + cl * 8);
                int2 pA = ldsn(e + 8);
                int2 pB = ldsn(e + 12);
                float nA = __int_as_float(sA.y);
                float nB = __int_as_float(sB.y);
                acc.x = fmaf(bflo(hA.x), nA, acc.x);
                acc.y = fmaf(bfhi(hA.x), nA, acc.y);
                acc.z = fmaf(bflo(hA.y), nA, acc.z);
                acc.w = fmaf(bfhi(hA.y), nA, acc.w);
                acc.x = fmaf(bflo(hB.x), nB, acc.x);
                acc.y = fmaf(bfhi(hB.x), nB, acc.y);
                acc.z = fmaf(bflo(hB.y), nB, acc.z);
                acc.w = fmaf(bfhi(hB.y), nB, acc.w);
                sA = pA; sB = pB;
            }
        }

        // cross-quarter reduce (lanes with same cl): xor 16, 32
        acc.x += __shfl_xor(acc.x, 16); acc.x += __shfl_xor(acc.x, 32);
        acc.y += __shfl_xor(acc.y, 16); acc.y += __shfl_xor(acc.y, 32);
        acc.z += __shfl_xor(acc.z, 16); acc.z += __shfl_xor(acc.z, 32);
        acc.w += __shfl_xor(acc.w, 16); acc.w += __shfl_xor(acc.w, 32);

        if (q == 0) {
            float4 val;
            val.x = fmaxf(acc.x + bias4.x, 0.f);
            val.y = fmaxf(acc.y + bias4.y, 0.f);
            val.z = fmaxf(acc.z + bias4.z, 0.f);
            val.w = fmaxf(acc.w + bias4.w, 0.f);
            if (WRITE_OUT) {
                ushort4 o;
                o.x = f2bf(val.x); o.y = f2bf(val.y);
                o.z = f2bf(val.z); o.w = f2bf(val.w);
                *reinterpret_cast<ushort4*>(out + (size_t)node * 64 + cl * 4) = o;
            } else {
                bsum.x += val.x; bsum.y += val.y; bsum.z += val.z; bsum.w += val.w;
            }
        }
    }

    if (!WRITE_OUT) {
        __shared__ float lds[4][64];
        const int wv = tid >> 6;
        if (q == 0) {
            lds[wv][cl * 4 + 0] = bsum.x;
            lds[wv][cl * 4 + 1] = bsum.y;
            lds[wv][cl * 4 + 2] = bsum.z;
            lds[wv][cl * 4 + 3] = bsum.w;
        }
        __syncthreads();
        if (tid < 64) {
            float s = lds[0][tid] + lds[1][tid] + lds[2][tid] + lds[3][tid];
            atomicAdd(&outsum[tid], s * inv_n);
        }
    }
}

extern "C" void kernel_launch(void* const* d_in, const int* in_sizes, int n_in,
                              void* d_out, int out_size, void* d_ws, size_t ws_size,
                              hipStream_t stream) {
    const float* x  = (const float*)d_in[0];
    const int*   ei = (const int*)d_in[1];
    const float* W1 = (const float*)d_in[2];
    const float* b1 = (const float*)d_in[3];
    const float* W2 = (const float*)d_in[4];
    const float* b2 = (const float*)d_in[5];

    const int n = in_sizes[0] / 128;   // 100000
    const int e = in_sizes[1] / 2;     // 3200000
    const int* src = ei;
    const int* dst = ei + e;
    const int nb = (n + 127) >> 7;     // 782 (<= 1024)

    char* ws = (char*)d_ws;
    size_t off = 0;
    auto alloc = [&](size_t bytes) { void* p = ws + off; off = (off + bytes + 255) & ~(size_t)255; return p; };
    unsigned* keys = (unsigned*)alloc((size_t)nb * CAP * 4);
    int*   bcur    = (int*)  alloc((size_t)nb * 4);
    int*   bbase   = (int*)  alloc((size_t)nb * 4);
    float* dis     = (float*)alloc((size_t)n * 4);
    int*   rowptr  = (int*)  alloc((size_t)(n + 1) * 4);
    int2*  csr_sn  = (int2*) alloc((size_t)e * 8);
    unsigned short* bufA = (unsigned short*)alloc((size_t)n * 64 * 2);
    unsigned short* bufB = (unsigned short*)alloc((size_t)n * 64 * 2);

    hipMemsetAsync(bcur, 0, (size_t)nb * 4, stream);
    hipMemsetAsync(d_out, 0, 64 * sizeof(float), stream);

    const int pa_blocks = (e + PA_T - 1) / PA_T;
    pass_a_kernel<<<pa_blocks, 256, 0, stream>>>(src, dst, bcur, keys, e, nb);
    bscan_kernel<<<1, 1024, 0, stream>>>(bcur, bbase, rowptr, nb, n);
    deg_dis_kernel<<<nb, 256, 0, stream>>>(keys, bcur, bbase, dis, rowptr, n);
    bucket_fill_kernel<<<nb, 256, 0, stream>>>(keys, bcur, bbase, dis, rowptr, csr_sn, n);

    const int gblocks = (n + 63) / 64;
    // Layer 1: h1 = x@W1 -> bufA (bf16)
    gemm_kernel<128, false><<<gblocks, 256, 0, stream>>>(x, W1, bufA, n);
    // x2 = relu(agg(h1) + b1) -> bufB (bf16)
    agg_kernel<true><<<2048, 256, 0, stream>>>(rowptr, csr_sn, bufA, dis, b1,
                                               bufB, nullptr, n, 0.f);
    // Layer 2: h2 = x2@W2 -> bufA (bf16)
    gemm_kernel<64, true><<<gblocks, 256, 0, stream>>>(bufB, W2, bufA, n);
    // out = mean_n relu(agg(h2) + b2)
    agg_kernel<false><<<2048, 256, 0, stream>>>(rowptr, csr_sn, bufA, dis, b2,
                                                nullptr, (float*)d_out, n, 1.0f / (float)n);
}

// Round 10
// 319.864 us; speedup vs baseline: 9.3694x; 1.0936x over previous
//
#include <hip/hip_runtime.h>

// GCN 2-layer + mean pool. fp8(e4m3) dis-prescaled feature tables, f32 math.
//   h'[r] = (x@W)[r] * dis[r]  (fused in GEMM epilogue)
//   out_d = relu( dis_d * ( sum_{j->d} h'[j] + h'[d] ) + bias )
// -> no per-edge norm; csr stream is 4 B/edge (src byte-offset); masked tail
//    lanes gather a dedicated zero row (row n).
// Build: pass_a (bucket by dst>>7) -> bscan -> deg_dis -> bucket_fill.
// Aggregate: wave-per-node, EIGHTH-split gather (8 rows per uint2 instr),
//    2-chunk pipeline (16 edges in flight), cross-lane shfl reduce.

#define CAP 8192
#define PA_T 4096

typedef float v2f __attribute__((vector_size(8)));

// unpack 4 fp8(e4m3) bytes -> 4 floats
__device__ __forceinline__ void fp8x4_to_f32(unsigned w, float* o) {
    v2f lo = __builtin_amdgcn_cvt_pk_f32_fp8((int)w, false);
    v2f hi = __builtin_amdgcn_cvt_pk_f32_fp8((int)w, true);
    o[0] = lo[0]; o[1] = lo[1]; o[2] = hi[0]; o[3] = hi[1];
}
// pack 4 floats -> 4 fp8(e4m3) bytes
__device__ __forceinline__ unsigned f32x4_to_fp8(float a, float b, float c, float d) {
    int w = 0;
    w = __builtin_amdgcn_cvt_pk_fp8_f32(a, b, w, false);
    w = __builtin_amdgcn_cvt_pk_fp8_f32(c, d, w, true);
    return (unsigned)w;
}

__global__ __launch_bounds__(256)
void pass_a_kernel(const int* __restrict__ src, const int* __restrict__ dst,
                   int* __restrict__ bcur, unsigned* __restrict__ keys, int e, int nb) {
    __shared__ unsigned skeys[PA_T];   // 16 KB
    __shared__ int hist[1024];
    __shared__ int base[1024];
    __shared__ int gbase[1024];
    __shared__ int curs[1024];
    __shared__ int tscan[256];

    const int tid = threadIdx.x;
    const int e0 = blockIdx.x * PA_T;
    const int cnt = min(PA_T, e - e0);

    for (int i = tid; i < 1024; i += 256) hist[i] = 0;
    __syncthreads();

    for (int i = tid; i < cnt; i += 256) {
        int d = dst[e0 + i];
        atomicAdd(&hist[d >> 7], 1);
    }
    __syncthreads();

    {   // exclusive scan of hist[0..1023]
        int t4 = tid * 4;
        int a0 = hist[t4], a1 = hist[t4 + 1], a2 = hist[t4 + 2], a3 = hist[t4 + 3];
        int tsum = a0 + a1 + a2 + a3;
        tscan[tid] = tsum;
        __syncthreads();
        for (int off = 1; off < 256; off <<= 1) {
            int v = (tid >= off) ? tscan[tid - off] : 0;
            __syncthreads();
            tscan[tid] += v;
            __syncthreads();
        }
        int ex = tscan[tid] - tsum;
        base[t4] = ex;
        base[t4 + 1] = ex + a0;
        base[t4 + 2] = ex + a0 + a1;
        base[t4 + 3] = ex + a0 + a1 + a2;
    }
    __syncthreads();
    for (int i = tid; i < 1024; i += 256) curs[i] = base[i];
    __syncthreads();

    for (int i = tid; i < cnt; i += 256) {
        int s = src[e0 + i], d = dst[e0 + i];
        int b = d >> 7;
        int pos = atomicAdd(&curs[b], 1);
        skeys[pos] = ((unsigned)s << 7) | (unsigned)(d & 127);
    }
    __syncthreads();

    for (int b = tid; b < nb; b += 256) {
        int c = hist[b];
        gbase[b] = c ? atomicAdd(&bcur[b], c) : 0;
    }
    __syncthreads();

    const int wv = tid >> 6, lane = tid & 63;
    for (int b = wv; b < nb; b += 4) {
        int lb = base[b], c = hist[b], gb = gbase[b];
        unsigned* dp = keys + (size_t)b * CAP + gb;
        for (int i = lane; i < c; i += 64) dp[i] = skeys[lb + i];
    }
}

__global__ __launch_bounds__(1024)
void bscan_kernel(const int* __restrict__ bcur, int* __restrict__ bbase,
                  int* __restrict__ rowptr, int nb, int n) {
    __shared__ int lds[1024];
    int t = threadIdx.x;
    int v = (t < nb) ? bcur[t] : 0;
    lds[t] = v;
    __syncthreads();
    for (int off = 1; off < 1024; off <<= 1) {
        int a = (t >= off) ? lds[t - off] : 0;
        __syncthreads();
        lds[t] += a;
        __syncthreads();
    }
    if (t < nb) bbase[t] = lds[t] - v;
    if (t == 1023) rowptr[n] = lds[1023];
}

__global__ __launch_bounds__(256)
void deg_dis_kernel(const unsigned* __restrict__ keys, const int* __restrict__ bcur,
                    const int* __restrict__ bbase, float* __restrict__ dis,
                    int* __restrict__ rowptr, int n) {
    __shared__ int hist[128];
    __shared__ int sc[256];
    const int tid = threadIdx.x;
    const int b = blockIdx.x;
    const int v0 = b << 7;
    const int nv = min(128, n - v0);
    const int ne = bcur[b];
    const int gb = bbase[b];
    const size_t kb = (size_t)b * CAP;

    if (tid < 128) hist[tid] = 0;
    __syncthreads();
    for (int i = tid; i < ne; i += 256) atomicAdd(&hist[keys[kb + i] & 127u], 1);
    __syncthreads();

    int hv = (tid < 128) ? hist[tid] : 0;
    sc[tid] = hv;
    __syncthreads();
    for (int off = 1; off < 128; off <<= 1) {
        int a = (tid >= off) ? sc[tid - off] : 0;
        __syncthreads();
        sc[tid] += a;
        __syncthreads();
    }
    if (tid < nv) {
        rowptr[v0 + tid] = gb + sc[tid] - hv;
        dis[v0 + tid] = rsqrtf((float)hv + 1.0f);
    }
}

// Per bucket: LDS counting sort -> src byte-offsets (s*64), coalesced.
__global__ __launch_bounds__(256)
void bucket_fill_kernel(const unsigned* __restrict__ keys, const int* __restrict__ bcur,
                        const int* __restrict__ bbase, const int* __restrict__ rowptr,
                        int* __restrict__ csr_src, int n) {
    __shared__ unsigned sk[CAP];   // 32 KB
    __shared__ int curs[128];

    const int tid = threadIdx.x;
    const int b = blockIdx.x;
    const int v0 = b << 7;
    const int nv = min(128, n - v0);
    const int ne = bcur[b];
    const int gb = bbase[b];
    const size_t kb = (size_t)b * CAP;

    if (tid < 128) curs[tid] = (tid < nv) ? (rowptr[v0 + tid] - gb) : ne;
    __syncthreads();

    for (int i = tid; i < ne; i += 256) {
        unsigned k = keys[kb + i];
        int pos = atomicAdd(&curs[k & 127u], 1);
        sk[pos] = k;
    }
    __syncthreads();

    for (int i = tid; i < ne; i += 256)
        csr_src[gb + i] = (int)((sk[i] >> 7) << 6);   // src * 64 bytes
}

// C_row = (A[n x K] @ B[K x 64]) * dis[row], stored fp8 e4m3 (64 B/row).
template <int K, bool FP8_IN>
__global__ __launch_bounds__(256)
void gemm_kernel(const void* __restrict__ Av, const float* __restrict__ B,
                 const float* __restrict__ dis, unsigned char* __restrict__ H, int n) {
    constexpr int KP = K + 4;
    __shared__ float As[64 * KP];
    __shared__ float Bs[K * 64];
    const int tid = threadIdx.x;
    const int row0 = blockIdx.x * 64;

    constexpr int A4 = 64 * (K / 4);
    for (int idx = tid; idx < A4; idx += 256) {
        int row = idx / (K / 4);
        int c4  = idx % (K / 4);
        float4 v = make_float4(0.f, 0.f, 0.f, 0.f);
        int r = row0 + row;
        if (r < n) {
            if (FP8_IN) {
                unsigned w = *reinterpret_cast<const unsigned*>(
                    (const unsigned char*)Av + (size_t)r * K + c4 * 4);
                float f[4];
                fp8x4_to_f32(w, f);
                v = make_float4(f[0], f[1], f[2], f[3]);
            } else {
                v = *reinterpret_cast<const float4*>((const float*)Av + (size_t)r * K + c4 * 4);
            }
        }
        *reinterpret_cast<float4*>(&As[row * KP + c4 * 4]) = v;
    }
    constexpr int B4 = K * 16;
    for (int idx = tid; idx < B4; idx += 256) {
        int row = idx / 16, c4 = idx % 16;
        *reinterpret_cast<float4*>(&Bs[row * 64 + c4 * 4]) =
            *reinterpret_cast<const float4*>(B + row * 64 + c4 * 4);
    }
    __syncthreads();

    const int tr = tid >> 4;
    const int tc = tid & 15;
    float acc[4][4];
#pragma unroll
    for (int j = 0; j < 4; ++j)
#pragma unroll
        for (int i = 0; i < 4; ++i) acc[j][i] = 0.f;

    for (int k4 = 0; k4 < K / 4; ++k4) {
        float4 a[4], bq[4];
#pragma unroll
        for (int j = 0; j < 4; ++j)
            a[j] = *reinterpret_cast<const float4*>(&As[(tr * 4 + j) * KP + k4 * 4]);
#pragma unroll
        for (int kk = 0; kk < 4; ++kk)
            bq[kk] = *reinterpret_cast<const float4*>(&Bs[(k4 * 4 + kk) * 64 + tc * 4]);
#pragma unroll
        for (int kk = 0; kk < 4; ++kk) {
#pragma unroll
            for (int j = 0; j < 4; ++j) {
                float av = (kk == 0) ? a[j].x : (kk == 1) ? a[j].y : (kk == 2) ? a[j].z : a[j].w;
                acc[j][0] = fmaf(av, bq[kk].x, acc[j][0]);
                acc[j][1] = fmaf(av, bq[kk].y, acc[j][1]);
                acc[j][2] = fmaf(av, bq[kk].z, acc[j][2]);
                acc[j][3] = fmaf(av, bq[kk].w, acc[j][3]);
            }
        }
    }

#pragma unroll
    for (int j = 0; j < 4; ++j) {
        int r = row0 + tr * 4 + j;
        if (r < n) {
            float ds = dis[r];
            unsigned w = f32x4_to_fp8(acc[j][0] * ds, acc[j][1] * ds,
                                      acc[j][2] * ds, acc[j][3] * ds);
            *reinterpret_cast<unsigned*>(H + (size_t)r * 64 + tc * 4) = w;
        }
    }
}

// One wave per dst node. lane = (o = lane>>3, cl = lane&7).
// Each uint2 gather fetches 8 fp8 rows (one per octant); channels cl*8..cl*8+7.
// Masked tail lanes gather the zero row at byte offset zoff = n*64.
template <bool WRITE_OUT>
__global__ __launch_bounds__(256)
void agg_kernel(const int* __restrict__ rowptr, const int* __restrict__ csr_src,
                const unsigned char* __restrict__ h, const float* __restrict__ dis,
                const float* __restrict__ bias,
                unsigned char* __restrict__ out, float* __restrict__ outsum,
                int n, int zoff, float inv_n) {
    const int tid = threadIdx.x;
    const int lane = tid & 63;
    const int o = lane >> 3;
    const int cl = lane & 7;
    const int wid = blockIdx.x * 4 + (tid >> 6);
    const int nw = gridDim.x * 4;

    float bl[8];
    {
        float4 b0 = *reinterpret_cast<const float4*>(bias + cl * 8);
        float4 b1 = *reinterpret_cast<const float4*>(bias + cl * 8 + 4);
        bl[0] = b0.x; bl[1] = b0.y; bl[2] = b0.z; bl[3] = b0.w;
        bl[4] = b1.x; bl[5] = b1.y; bl[6] = b1.z; bl[7] = b1.w;
    }
    float bsum[8];
#pragma unroll
    for (int k = 0; k < 8; ++k) bsum[k] = 0.f;

    for (int node = wid; node < n; node += nw) {
        const int st = rowptr[node];
        const int en = rowptr[node + 1];
        const float ds = dis[node];
        float acc[8];
        {   // self row: only octant 0 contributes
            uint2 hw = *reinterpret_cast<const uint2*>(h + (size_t)node * 64 + cl * 8);
            float sf = (o == 0) ? 1.f : 0.f;
            float f[8];
            fp8x4_to_f32(hw.x, f);
            fp8x4_to_f32(hw.y, f + 4);
#pragma unroll
            for (int k = 0; k < 8; ++k) acc[k] = f[k] * sf;
        }
        if (en > st) {
            auto ldof = [&](int bse) -> int {
                int idx = bse + o;
                int v = csr_src[min(idx, en - 1)];
                return (idx < en) ? v : zoff;
            };
            int e = st;
            int oA = ldof(e);
            int oB = ldof(e + 8);
            for (; e < en; e += 16) {
                uint2 hA = *reinterpret_cast<const uint2*>(h + (size_t)(unsigned)oA + cl * 8);
                uint2 hB = *reinterpret_cast<const uint2*>(h + (size_t)(unsigned)oB + cl * 8);
                int pA = ldof(e + 16);
                int pB = ldof(e + 24);
                float fA[8], fB[8];
                fp8x4_to_f32(hA.x, fA);
                fp8x4_to_f32(hA.y, fA + 4);
                fp8x4_to_f32(hB.x, fB);
                fp8x4_to_f32(hB.y, fB + 4);
#pragma unroll
                for (int k = 0; k < 8; ++k) acc[k] += fA[k] + fB[k];
                oA = pA; oB = pB;
            }
        }
#pragma unroll
        for (int k = 0; k < 8; ++k) {
            float v = acc[k];
            v += __shfl_xor(v, 8);
            v += __shfl_xor(v, 16);
            v += __shfl_xor(v, 32);
            acc[k] = v;
        }
        if (o == 0) {
            float val[8];
#pragma unroll
            for (int k = 0; k < 8; ++k) val[k] = fmaxf(fmaf(acc[k], ds, bl[k]), 0.f);
            if (WRITE_OUT) {
                unsigned w0 = f32x4_to_fp8(val[0], val[1], val[2], val[3]);
                unsigned w1 = f32x4_to_fp8(val[4], val[5], val[6], val[7]);
                *reinterpret_cast<uint2*>(out + (size_t)node * 64 + cl * 8) = make_uint2(w0, w1);
            } else {
#pragma unroll
                for (int k = 0; k < 8; ++k) bsum[k] += val[k];
            }
        }
    }

    if (!WRITE_OUT) {
        __shared__ float lds[4][64];
        const int wv = tid >> 6;
        if (o == 0) {
#pragma unroll
            for (int k = 0; k < 8; ++k) lds[wv][cl * 8 + k] = bsum[k];
        }
        __syncthreads();
        if (tid < 64) {
            float s = lds[0][tid] + lds[1][tid] + lds[2][tid] + lds[3][tid];
            atomicAdd(&outsum[tid], s * inv_n);
        }
    }
}

extern "C" void kernel_launch(void* const* d_in, const int* in_sizes, int n_in,
                              void* d_out, int out_size, void* d_ws, size_t ws_size,
                              hipStream_t stream) {
    const float* x  = (const float*)d_in[0];
    const int*   ei = (const int*)d_in[1];
    const float* W1 = (const float*)d_in[2];
    const float* b1 = (const float*)d_in[3];
    const float* W2 = (const float*)d_in[4];
    const float* b2 = (const float*)d_in[5];

    const int n = in_sizes[0] / 128;   // 100000
    const int e = in_sizes[1] / 2;     // 3200000
    const int* src = ei;
    const int* dst = ei + e;
    const int nb = (n + 127) >> 7;     // 782 (<= 1024)

    char* ws = (char*)d_ws;
    size_t off = 0;
    auto alloc = [&](size_t bytes) { void* p = ws + off; off = (off + bytes + 255) & ~(size_t)255; return p; };
    unsigned* keys = (unsigned*)alloc((size_t)nb * CAP * 4);
    int*   bcur    = (int*)  alloc((size_t)nb * 4);
    int*   bbase   = (int*)  alloc((size_t)nb * 4);
    float* dis     = (float*)alloc((size_t)n * 4);
    int*   rowptr  = (int*)  alloc((size_t)(n + 1) * 4);
    int*   csr_src = (int*)  alloc((size_t)e * 4);
    unsigned char* bufA = (unsigned char*)alloc((size_t)(n + 1) * 64);  // + zero row
    unsigned char* bufB = (unsigned char*)alloc((size_t)(n + 1) * 64);

    hipMemsetAsync(bcur, 0, (size_t)nb * 4, stream);
    hipMemsetAsync(d_out, 0, 64 * sizeof(float), stream);
    hipMemsetAsync(bufA + (size_t)n * 64, 0, 64, stream);   // zero row for masked tail gathers

    const int pa_blocks = (e + PA_T - 1) / PA_T;
    pass_a_kernel<<<pa_blocks, 256, 0, stream>>>(src, dst, bcur, keys, e, nb);
    bscan_kernel<<<1, 1024, 0, stream>>>(bcur, bbase, rowptr, nb, n);
    deg_dis_kernel<<<nb, 256, 0, stream>>>(keys, bcur, bbase, dis, rowptr, n);
    bucket_fill_kernel<<<nb, 256, 0, stream>>>(keys, bcur, bbase, rowptr, csr_src, n);

    const int gblocks = (n + 63) / 64;
    const int zoff = n * 64;
    // Layer 1: h1' = (x@W1)*dis -> bufA (fp8)
    gemm_kernel<128, false><<<gblocks, 256, 0, stream>>>(x, W1, dis, bufA, n);
    // x2 = relu(dis * (gather-sum of h1') + b1) -> bufB (fp8)
    agg_kernel<true><<<2048, 256, 0, stream>>>(rowptr, csr_src, bufA, dis, b1,
                                               bufB, nullptr, n, zoff, 0.f);
    // Layer 2: h2' = (x2@W2)*dis -> bufA (fp8; overwrites h1', zero row preserved)
    gemm_kernel<64, true><<<gblocks, 256, 0, stream>>>(bufB, W2, dis, bufA, n);
    // out = mean_n relu(dis * (gather-sum of h2') + b2)
    agg_kernel<false><<<2048, 256, 0, stream>>>(rowptr, csr_src, bufA, dis, b2,
                                                nullptr, (float*)d_out, n, zoff, 1.0f / (float)n);
}